// Round 6
// baseline (411.416 us; speedup 1.0000x reference)
//
#include <hip/hip_runtime.h>
#include <hip/hip_bf16.h>

// Problem dims (StandardAttention): x[4,96,256,256], heads=3
#define B_  4
#define C_  96
#define H_  256
#define W_  256
#define N_  (H_*W_)      // 65536
#define C3_ 288
#define HEAD_ 3
#define HC_ 32
#define EPS_ 1e-12f
#define SPLITS_ 128      // split-K segments for QK^T

typedef __attribute__((ext_vector_type(8))) short short8;
typedef __attribute__((ext_vector_type(4))) float f32x4;

// ---- bf16 helpers (raw ushort storage) -------------------------------------
__device__ __forceinline__ unsigned short f2bf(float f) {
  unsigned u = __float_as_uint(f);
  u += 0x7fffu + ((u >> 16) & 1u);      // round-to-nearest-even
  return (unsigned short)(u >> 16);
}
__device__ __forceinline__ float bf2f(unsigned short h) {
  return __uint_as_float((unsigned)h << 16);
}
__device__ __forceinline__ float bf_lo(unsigned u) { return __uint_as_float(u << 16); }
__device__ __forceinline__ float bf_hi(unsigned u) { return __uint_as_float(u & 0xffff0000u); }
__device__ __forceinline__ unsigned pack_bf(float a, float b) {
  return (unsigned)f2bf(a) | ((unsigned)f2bf(b) << 16);
}

// ---------------- K0: fp32 -> bf16 cast (for qkv weights) -------------------
__global__ __launch_bounds__(256) void k_cast(
    const float* __restrict__ s, unsigned short* __restrict__ d, int n) {
  const int i = blockIdx.x * 256 + threadIdx.x;
  if (i < n) d[i] = f2bf(s[i]);
}

// ---------------- K1: qkv = qkv_w @ x + qkv_b  via MFMA, NO LDS -------------
// Wave = 16 pixels x all 288 out-channels. A-frags (W rows) and B-frags
// (x channel-columns) both straight from global; no barriers.
__global__ __launch_bounds__(256) void k1_mfma(
    const float* __restrict__ x, const unsigned short* __restrict__ wbf,
    const float* __restrict__ bias, unsigned short* __restrict__ out) {
  const int tid = threadIdx.x;
  const int b = blockIdx.y;
  const int lane = tid & 63;
  const int wv = tid >> 6;
  const int l15 = lane & 15, quad = lane >> 4;
  const int gpix = blockIdx.x * 64 + wv * 16 + l15;   // this lane's pixel
  const float* xcol = x + (size_t)b * C_ * N_ + gpix;
  short8 bfr[3];
#pragma unroll
  for (int kc = 0; kc < 3; ++kc) {
#pragma unroll
    for (int u = 0; u < 8; ++u)
      bfr[kc][u] = (short)f2bf(xcol[(size_t)(kc * 32 + quad * 8 + u) * N_]);
  }
  f32x4 acc[18];
#pragma unroll
  for (int m = 0; m < 18; ++m) acc[m] = (f32x4){0.f, 0.f, 0.f, 0.f};
#pragma unroll
  for (int m = 0; m < 18; ++m) {
#pragma unroll
    for (int kc = 0; kc < 3; ++kc) {
      const short8 afr = *reinterpret_cast<const short8*>(
          wbf + (m * 16 + l15) * C_ + kc * 32 + quad * 8);
      acc[m] = __builtin_amdgcn_mfma_f32_16x16x32_bf16(afr, bfr[kc], acc[m], 0, 0, 0);
    }
  }
  unsigned short* ob = out + (size_t)b * C3_ * N_ + gpix;
#pragma unroll
  for (int m = 0; m < 18; ++m) {
    const int chb = m * 16 + quad * 4;
#pragma unroll
    for (int r = 0; r < 4; ++r)
      ob[(size_t)(chb + r) * N_] = f2bf(acc[m][r] + bias[chb + r]);
  }
}

// ---------------- K2: 3x3 depthwise conv IN-PLACE, register-rolling ---------
__global__ __launch_bounds__(256) void k_dw_reg(
    unsigned short* a, const float* __restrict__ w9,
    const float* __restrict__ bias, float* __restrict__ inv) {
  const int bc = blockIdx.x;            // 0..1151
  const int ch = bc % C3_;
  unsigned short* p = a + (size_t)bc * N_;
  const int tid = threadIdx.x;
  const int tr = tid >> 5;              // 0..7 row segment
  const int tc = tid & 31;
  const int x0 = tc * 8;
  const int y0 = tr * 32;
  float wv[9];
#pragma unroll
  for (int i = 0; i < 9; ++i) wv[i] = w9[ch * 9 + i];
  const float bv = bias[ch];

  auto load_row = [&](int y, float* d) {
    if ((unsigned)y >= 256u) {
#pragma unroll
      for (int j = 0; j < 10; ++j) d[j] = 0.f;
      return;
    }
    const unsigned short* rp = p + (size_t)y * W_;
    const uint4 u = *reinterpret_cast<const uint4*>(rp + x0);
    d[1] = bf_lo(u.x); d[2] = bf_hi(u.x); d[3] = bf_lo(u.y); d[4] = bf_hi(u.y);
    d[5] = bf_lo(u.z); d[6] = bf_hi(u.z); d[7] = bf_lo(u.w); d[8] = bf_hi(u.w);
    d[0] = (tc > 0) ? bf2f(rp[x0 - 1]) : 0.f;
    d[9] = (tc < 31) ? bf2f(rp[x0 + 8]) : 0.f;
  };

  float rm[10], rc[10], rn[10], rb[10];
  load_row(y0 - 1, rm);
  load_row(y0, rc);
  load_row(y0 + 1, rn);
  load_row(y0 + 32, rb);     // bottom boundary: original data, pre-barrier
  __syncthreads();           // all preloads done before any write

  float ss = 0.f;
  for (int y = y0; y < y0 + 32; ++y) {
    float o[8];
#pragma unroll
    for (int j = 0; j < 8; ++j) {
      o[j] = bv + wv[0] * rm[j] + wv[1] * rm[j + 1] + wv[2] * rm[j + 2]
                + wv[3] * rc[j] + wv[4] * rc[j + 1] + wv[5] * rc[j + 2]
                + wv[6] * rn[j] + wv[7] * rn[j + 1] + wv[8] * rn[j + 2];
      ss += o[j] * o[j];
    }
    uint4 st;
    st.x = pack_bf(o[0], o[1]); st.y = pack_bf(o[2], o[3]);
    st.z = pack_bf(o[4], o[5]); st.w = pack_bf(o[6], o[7]);
    *reinterpret_cast<uint4*>(p + (size_t)y * W_ + x0) = st;
#pragma unroll
    for (int j = 0; j < 10; ++j) { rm[j] = rc[j]; rc[j] = rn[j]; }
    const int ny = y + 2;
    if (ny <= y0 + 31) {
      load_row(ny, rn);
    } else if (ny == y0 + 32) {
#pragma unroll
      for (int j = 0; j < 10; ++j) rn[j] = rb[j];
    }
  }
#pragma unroll
  for (int off = 32; off > 0; off >>= 1) ss += __shfl_down(ss, off, 64);
  __shared__ float red[4];
  if ((tid & 63) == 0) red[tid >> 6] = ss;
  __syncthreads();
  if (tid == 0 && ch < 192) {
    const float t = red[0] + red[1] + red[2] + red[3];
    const int b = bc / C3_;
    inv[b * 192 + ch] = 1.0f / fmaxf(sqrtf(t), EPS_);
  }
}

// ---------------- K4: QK^T via MFMA, split-K partials (no atomics) ----------
__global__ __launch_bounds__(256) void k_attn_mfma(
    const unsigned short* __restrict__ dw, float* __restrict__ part) {
  const int tid = threadIdx.x;
  const int lane = tid & 63;
  const int wv = tid >> 6;
  const int i0 = (wv >> 1) * 16, j0 = (wv & 1) * 16;
  const int h = blockIdx.y, b = blockIdx.z;
  const int n0 = blockIdx.x * (N_ / SPLITS_);    // 512-px segment
  const int l15 = lane & 15, quad = lane >> 4;
  const unsigned short* qrow =
      dw + ((size_t)(b * C3_ + h * HC_ + i0 + l15)) * N_ + n0 + quad * 8;
  const unsigned short* krow =
      dw + ((size_t)(b * C3_ + C_ + h * HC_ + j0 + l15)) * N_ + n0 + quad * 8;
  f32x4 acc = (f32x4){0.f, 0.f, 0.f, 0.f};
#pragma unroll 4
  for (int s = 0; s < N_ / SPLITS_; s += 32) {
    const short8 af = *reinterpret_cast<const short8*>(qrow + s);
    const short8 bf = *reinterpret_cast<const short8*>(krow + s);
    acc = __builtin_amdgcn_mfma_f32_16x16x32_bf16(af, bf, acc, 0, 0, 0);
  }
  float* pp = part + (size_t)blockIdx.x * (B_ * HEAD_ * 1024)
                   + ((size_t)(b * HEAD_ + h)) * 1024;
#pragma unroll
  for (int r = 0; r < 4; ++r)
    pp[(i0 + quad * 4 + r) * 32 + j0 + l15] = acc[r];
}

// ---------------- K5: reduce partials, scale by inv norms, softmax ----------
__global__ __launch_bounds__(256) void k_softmax(
    const float* __restrict__ part, const float* __restrict__ inv,
    float* __restrict__ attn_out) {
  const int tid = threadIdx.x;
  const int R = blockIdx.x * 8 + (tid >> 5);   // 0..383 = (b*3+h)*32+i
  const int j = tid & 31;
  const int b = R / 96, rem = R % 96;
  const int h = rem / 32, i = rem % 32;
  float v = 0.f;
  for (int s = 0; s < SPLITS_; ++s)
    v += part[(size_t)s * (B_ * HEAD_ * 1024) + R * 32 + j];
  const float invq = inv[b * 192 + h * 32 + i];
  const float invk = inv[b * 192 + 96 + h * 32 + j];
  v *= invq * invk;                             // TEMP = 1
  float m = v;
#pragma unroll
  for (int off = 16; off > 0; off >>= 1) m = fmaxf(m, __shfl_xor(m, off, 32));
  const float e = __expf(v - m);
  float s = e;
#pragma unroll
  for (int off = 16; off > 0; off >>= 1) s += __shfl_xor(s, off, 32);
  attn_out[R * 32 + j] = e / s;
}

// ---------------- K6: M_b = proj_w o attn  (per-batch 96x96, bf16) ----------
// M[o][h*32+j] = sum_i proj[o][h*32+i] * attn[b][h][i][j]
__global__ __launch_bounds__(256) void k_M(
    const float* __restrict__ attn, const float* __restrict__ proj_w,
    unsigned short* __restrict__ Mbf) {
  const int b = blockIdx.x;
  const int tid = threadIdx.x;
  __shared__ float As[HEAD_ * 1024];
  for (int l = tid; l < HEAD_ * 1024; l += 256)
    As[l] = attn[(size_t)b * HEAD_ * 1024 + l];
  __syncthreads();
  for (int e = tid; e < C_ * C_; e += 256) {
    const int o = e / 96, jj = e % 96;
    const int h = jj >> 5, j = jj & 31;
    float s = 0.f;
#pragma unroll
    for (int i = 0; i < 32; ++i)
      s += proj_w[o * 96 + h * 32 + i] * As[h * 1024 + i * 32 + j];
    Mbf[(size_t)b * C_ * C_ + e] = f2bf(s);
  }
}

// ---------------- K7: out = M_b @ v + proj_b via MFMA, NO LDS ---------------
__global__ __launch_bounds__(256) void k7_mfma(
    const unsigned short* __restrict__ A /* workspace base */,
    const unsigned short* __restrict__ Mbf,
    const float* __restrict__ bias, float* __restrict__ out) {
  const int tid = threadIdx.x;
  const int b = blockIdx.y;
  const int lane = tid & 63;
  const int wv = tid >> 6;
  const int l15 = lane & 15, quad = lane >> 4;
  const int gpix = blockIdx.x * 64 + wv * 16 + l15;
  const unsigned short* vcol = A + ((size_t)(b * C3_ + 2 * C_)) * N_ + gpix;
  const unsigned short* Mb = Mbf + (size_t)b * C_ * C_;
  short8 bfr[3];
#pragma unroll
  for (int kc = 0; kc < 3; ++kc) {
#pragma unroll
    for (int u = 0; u < 8; ++u)
      bfr[kc][u] = (short)vcol[(size_t)(kc * 32 + quad * 8 + u) * N_];
  }
  f32x4 acc[6];
#pragma unroll
  for (int m = 0; m < 6; ++m) acc[m] = (f32x4){0.f, 0.f, 0.f, 0.f};
#pragma unroll
  for (int m = 0; m < 6; ++m) {
#pragma unroll
    for (int kc = 0; kc < 3; ++kc) {
      const short8 afr = *reinterpret_cast<const short8*>(
          Mb + (m * 16 + l15) * C_ + kc * 32 + quad * 8);
      acc[m] = __builtin_amdgcn_mfma_f32_16x16x32_bf16(afr, bfr[kc], acc[m], 0, 0, 0);
    }
  }
  float* ob = out + (size_t)b * C_ * N_ + gpix;
#pragma unroll
  for (int m = 0; m < 6; ++m) {
    const int chb = m * 16 + quad * 4;
#pragma unroll
    for (int r = 0; r < 4; ++r)
      ob[(size_t)(chb + r) * N_] = acc[m][r] + bias[chb + r];
  }
}

extern "C" void kernel_launch(void* const* d_in, const int* in_sizes, int n_in,
                              void* d_out, int out_size, void* d_ws, size_t ws_size,
                              hipStream_t stream) {
  const float* x      = (const float*)d_in[0];
  const float* qkv_w  = (const float*)d_in[1];
  const float* qkv_b  = (const float*)d_in[2];
  const float* dw_w   = (const float*)d_in[3];
  const float* dw_b   = (const float*)d_in[4];
  const float* proj_w = (const float*)d_in[5];
  const float* proj_b = (const float*)d_in[6];

  float* out      = (float*)d_out;                       // [4,96,256,256]
  float* attn_out = out + (size_t)B_ * C_ * N_;          // [4,3,32,32]

  // Workspace: A 151MB | inv 3KB | part 6.3MB | wq_bf 55KB | Mbf 74KB
  unsigned short* A = (unsigned short*)d_ws;
  float* inv   = (float*)(A + (size_t)B_ * C3_ * N_);
  float* part  = inv + 768;
  unsigned short* wq_bf = (unsigned short*)(part + SPLITS_ * B_ * HEAD_ * 1024);
  unsigned short* Mbf   = wq_bf + C3_ * C_;

  k_cast<<<108, 256, 0, stream>>>(qkv_w, wq_bf, C3_ * C_);
  k1_mfma<<<dim3(N_ / 64, B_), 256, 0, stream>>>(x, wq_bf, qkv_b, A);
  k_dw_reg<<<B_ * C3_, 256, 0, stream>>>(A, dw_w, dw_b, inv);
  k_attn_mfma<<<dim3(SPLITS_, HEAD_, B_), 256, 0, stream>>>(A, part);
  k_softmax<<<48, 256, 0, stream>>>(part, inv, attn_out);
  k_M<<<B_, 256, 0, stream>>>(attn_out, proj_w, Mbf);
  k7_mfma<<<dim3(N_ / 64, B_), 256, 0, stream>>>(A, Mbf, proj_b, out);
}

// Round 7
// 360.980 us; speedup vs baseline: 1.1397x; 1.1397x over previous
//
#include <hip/hip_runtime.h>
#include <hip/hip_bf16.h>

// Problem dims (StandardAttention): x[4,96,256,256], heads=3
#define B_  4
#define C_  96
#define H_  256
#define W_  256
#define N_  (H_*W_)      // 65536
#define C3_ 288
#define HEAD_ 3
#define HC_ 32
#define EPS_ 1e-12f
#define XP_ 104          // padded LDS row stride (ushorts): 52 words -> 2 lanes/bank (free)
#define SPLITS_ 128      // split-K segments for QK^T

typedef __attribute__((ext_vector_type(8))) short short8;
typedef __attribute__((ext_vector_type(4))) float f32x4;

// ---- bf16 helpers (raw ushort storage) -------------------------------------
__device__ __forceinline__ unsigned short f2bf(float f) {
  unsigned u = __float_as_uint(f);
  u += 0x7fffu + ((u >> 16) & 1u);      // round-to-nearest-even
  return (unsigned short)(u >> 16);
}
__device__ __forceinline__ float bf2f(unsigned short h) {
  return __uint_as_float((unsigned)h << 16);
}
__device__ __forceinline__ float bf_lo(unsigned u) { return __uint_as_float(u << 16); }
__device__ __forceinline__ float bf_hi(unsigned u) { return __uint_as_float(u & 0xffff0000u); }
__device__ __forceinline__ unsigned pack_bf(float a, float b) {
  return (unsigned)f2bf(a) | ((unsigned)f2bf(b) << 16);
}

// ---------------- K0: fp32 -> bf16 cast (for qkv weights) -------------------
__global__ __launch_bounds__(256) void k_cast(
    const float* __restrict__ s, unsigned short* __restrict__ d, int n) {
  const int i = blockIdx.x * 256 + threadIdx.x;
  if (i < n) d[i] = f2bf(s[i]);
}

// ---------------- K1: qkv = qkv_w @ x + qkv_b via MFMA ----------------------
// 512 threads = 8 waves x 16 px = 128-px tile. W staged in LDS ONCE (conflict-
// free padded rows), single barrier; B-frags straight from global (L3-hot);
// A-frags via ds_read_b128; no per-tile barriers.
__global__ __launch_bounds__(512) void k1_mfma(
    const float* __restrict__ x, const unsigned short* __restrict__ wbf,
    const float* __restrict__ bias, unsigned short* __restrict__ out) {
  __shared__ unsigned short Wl[C3_ * XP_];    // 59904 B
  __shared__ float Bl[C3_];
  const int tid = threadIdx.x;
  const int b = blockIdx.y;
  for (int i = tid; i < C3_ * C_; i += 512)
    Wl[(i / 96) * XP_ + (i % 96)] = wbf[i];
  for (int i = tid; i < C3_; i += 512) Bl[i] = bias[i];
  __syncthreads();
  const int lane = tid & 63;
  const int wv = tid >> 6;                    // 0..7
  const int l15 = lane & 15, quad = lane >> 4;
  const int gpix = blockIdx.x * 128 + wv * 16 + l15;
  const float* xcol = x + (size_t)b * C_ * N_ + gpix;
  short8 bfr[3];
#pragma unroll
  for (int kc = 0; kc < 3; ++kc) {
#pragma unroll
    for (int u = 0; u < 8; ++u)
      bfr[kc][u] = (short)f2bf(xcol[(size_t)(kc * 32 + quad * 8 + u) * N_]);
  }
  f32x4 acc[18];
#pragma unroll
  for (int m = 0; m < 18; ++m) acc[m] = (f32x4){0.f, 0.f, 0.f, 0.f};
#pragma unroll
  for (int m = 0; m < 18; ++m) {
#pragma unroll
    for (int kc = 0; kc < 3; ++kc) {
      const short8 afr = *reinterpret_cast<const short8*>(
          &Wl[(m * 16 + l15) * XP_ + kc * 32 + quad * 8]);
      acc[m] = __builtin_amdgcn_mfma_f32_16x16x32_bf16(afr, bfr[kc], acc[m], 0, 0, 0);
    }
  }
  unsigned short* ob = out + (size_t)b * C3_ * N_ + gpix;
#pragma unroll
  for (int m = 0; m < 18; ++m) {
    const int chb = m * 16 + quad * 4;
#pragma unroll
    for (int r = 0; r < 4; ++r)
      ob[(size_t)(chb + r) * N_] = f2bf(acc[m][r] + Bl[chb + r]);
  }
}

// ---------------- K2: 3x3 depthwise conv IN-PLACE, register-rolling ---------
__global__ __launch_bounds__(256) void k_dw_reg(
    unsigned short* a, const float* __restrict__ w9,
    const float* __restrict__ bias, float* __restrict__ inv) {
  const int bc = blockIdx.x;            // 0..1151
  const int ch = bc % C3_;
  unsigned short* p = a + (size_t)bc * N_;
  const int tid = threadIdx.x;
  const int tr = tid >> 5;              // 0..7 row segment
  const int tc = tid & 31;
  const int x0 = tc * 8;
  const int y0 = tr * 32;
  float wv[9];
#pragma unroll
  for (int i = 0; i < 9; ++i) wv[i] = w9[ch * 9 + i];
  const float bv = bias[ch];

  auto load_row = [&](int y, float* d) {
    if ((unsigned)y >= 256u) {
#pragma unroll
      for (int j = 0; j < 10; ++j) d[j] = 0.f;
      return;
    }
    const unsigned short* rp = p + (size_t)y * W_;
    const uint4 u = *reinterpret_cast<const uint4*>(rp + x0);
    d[1] = bf_lo(u.x); d[2] = bf_hi(u.x); d[3] = bf_lo(u.y); d[4] = bf_hi(u.y);
    d[5] = bf_lo(u.z); d[6] = bf_hi(u.z); d[7] = bf_lo(u.w); d[8] = bf_hi(u.w);
    d[0] = (tc > 0) ? bf2f(rp[x0 - 1]) : 0.f;
    d[9] = (tc < 31) ? bf2f(rp[x0 + 8]) : 0.f;
  };

  float rm[10], rc[10], rn[10], rb[10];
  load_row(y0 - 1, rm);
  load_row(y0, rc);
  load_row(y0 + 1, rn);
  load_row(y0 + 32, rb);     // bottom boundary: original data, pre-barrier
  __syncthreads();           // all preloads done before any write

  float ss = 0.f;
  for (int y = y0; y < y0 + 32; ++y) {
    float o[8];
#pragma unroll
    for (int j = 0; j < 8; ++j) {
      o[j] = bv + wv[0] * rm[j] + wv[1] * rm[j + 1] + wv[2] * rm[j + 2]
                + wv[3] * rc[j] + wv[4] * rc[j + 1] + wv[5] * rc[j + 2]
                + wv[6] * rn[j] + wv[7] * rn[j + 1] + wv[8] * rn[j + 2];
      ss += o[j] * o[j];
    }
    uint4 st;
    st.x = pack_bf(o[0], o[1]); st.y = pack_bf(o[2], o[3]);
    st.z = pack_bf(o[4], o[5]); st.w = pack_bf(o[6], o[7]);
    *reinterpret_cast<uint4*>(p + (size_t)y * W_ + x0) = st;
#pragma unroll
    for (int j = 0; j < 10; ++j) { rm[j] = rc[j]; rc[j] = rn[j]; }
    const int ny = y + 2;
    if (ny <= y0 + 31) {
      load_row(ny, rn);
    } else if (ny == y0 + 32) {
#pragma unroll
      for (int j = 0; j < 10; ++j) rn[j] = rb[j];
    }
  }
#pragma unroll
  for (int off = 32; off > 0; off >>= 1) ss += __shfl_down(ss, off, 64);
  __shared__ float red[4];
  if ((tid & 63) == 0) red[tid >> 6] = ss;
  __syncthreads();
  if (tid == 0 && ch < 192) {
    const float t = red[0] + red[1] + red[2] + red[3];
    const int b = bc / C3_;
    inv[b * 192 + ch] = 1.0f / fmaxf(sqrtf(t), EPS_);
  }
}

// ---------------- K4: QK^T via MFMA, split-K partials (no atomics) ----------
__global__ __launch_bounds__(256) void k_attn_mfma(
    const unsigned short* __restrict__ dw, float* __restrict__ part) {
  const int tid = threadIdx.x;
  const int lane = tid & 63;
  const int wv = tid >> 6;
  const int i0 = (wv >> 1) * 16, j0 = (wv & 1) * 16;
  const int h = blockIdx.y, b = blockIdx.z;
  const int n0 = blockIdx.x * (N_ / SPLITS_);    // 512-px segment
  const int l15 = lane & 15, quad = lane >> 4;
  const unsigned short* qrow =
      dw + ((size_t)(b * C3_ + h * HC_ + i0 + l15)) * N_ + n0 + quad * 8;
  const unsigned short* krow =
      dw + ((size_t)(b * C3_ + C_ + h * HC_ + j0 + l15)) * N_ + n0 + quad * 8;
  f32x4 acc = (f32x4){0.f, 0.f, 0.f, 0.f};
#pragma unroll 4
  for (int s = 0; s < N_ / SPLITS_; s += 32) {
    const short8 af = *reinterpret_cast<const short8*>(qrow + s);
    const short8 bf = *reinterpret_cast<const short8*>(krow + s);
    acc = __builtin_amdgcn_mfma_f32_16x16x32_bf16(af, bf, acc, 0, 0, 0);
  }
  float* pp = part + (size_t)blockIdx.x * (B_ * HEAD_ * 1024)
                   + ((size_t)(b * HEAD_ + h)) * 1024;
#pragma unroll
  for (int r = 0; r < 4; ++r)
    pp[(i0 + quad * 4 + r) * 32 + j0 + l15] = acc[r];
}

// ---------------- K5: reduce partials, scale by inv norms, softmax ----------
__global__ __launch_bounds__(256) void k_softmax(
    const float* __restrict__ part, const float* __restrict__ inv,
    float* __restrict__ attn_out) {
  const int tid = threadIdx.x;
  const int R = blockIdx.x * 8 + (tid >> 5);   // 0..383 = (b*3+h)*32+i
  const int j = tid & 31;
  const int b = R / 96, rem = R % 96;
  const int h = rem / 32, i = rem % 32;
  float v = 0.f;
  for (int s = 0; s < SPLITS_; ++s)
    v += part[(size_t)s * (B_ * HEAD_ * 1024) + R * 32 + j];
  const float invq = inv[b * 192 + h * 32 + i];
  const float invk = inv[b * 192 + 96 + h * 32 + j];
  v *= invq * invk;                             // TEMP = 1
  float m = v;
#pragma unroll
  for (int off = 16; off > 0; off >>= 1) m = fmaxf(m, __shfl_xor(m, off, 32));
  const float e = __expf(v - m);
  float s = e;
#pragma unroll
  for (int off = 16; off > 0; off >>= 1) s += __shfl_xor(s, off, 32);
  attn_out[R * 32 + j] = e / s;
}

// ---------------- K6: M_b = proj_w o attn  (per-batch 96x96, bf16) ----------
__global__ __launch_bounds__(256) void k_M(
    const float* __restrict__ attn, const float* __restrict__ proj_w,
    unsigned short* __restrict__ Mbf) {
  const int b = blockIdx.x;
  const int tid = threadIdx.x;
  __shared__ float As[HEAD_ * 1024];
  for (int l = tid; l < HEAD_ * 1024; l += 256)
    As[l] = attn[(size_t)b * HEAD_ * 1024 + l];
  __syncthreads();
  for (int e = tid; e < C_ * C_; e += 256) {
    const int o = e / 96, jj = e % 96;
    const int h = jj >> 5, j = jj & 31;
    float s = 0.f;
#pragma unroll
    for (int i = 0; i < 32; ++i)
      s += proj_w[o * 96 + h * 32 + i] * As[h * 1024 + i * 32 + j];
    Mbf[(size_t)b * C_ * C_ + e] = f2bf(s);
  }
}

// ---------------- K7: out = M_b @ v + proj_b via MFMA, NO LDS ---------------
// M is 18KB bf16 -> fits L1, so global A-frag reads are cheap here.
__global__ __launch_bounds__(256) void k7_mfma(
    const unsigned short* __restrict__ A /* workspace base */,
    const unsigned short* __restrict__ Mbf,
    const float* __restrict__ bias, float* __restrict__ out) {
  const int tid = threadIdx.x;
  const int b = blockIdx.y;
  const int lane = tid & 63;
  const int wv = tid >> 6;
  const int l15 = lane & 15, quad = lane >> 4;
  const int gpix = blockIdx.x * 64 + wv * 16 + l15;
  const unsigned short* vcol = A + ((size_t)(b * C3_ + 2 * C_)) * N_ + gpix;
  const unsigned short* Mb = Mbf + (size_t)b * C_ * C_;
  short8 bfr[3];
#pragma unroll
  for (int kc = 0; kc < 3; ++kc) {
#pragma unroll
    for (int u = 0; u < 8; ++u)
      bfr[kc][u] = (short)vcol[(size_t)(kc * 32 + quad * 8 + u) * N_];
  }
  f32x4 acc[6];
#pragma unroll
  for (int m = 0; m < 6; ++m) acc[m] = (f32x4){0.f, 0.f, 0.f, 0.f};
#pragma unroll
  for (int m = 0; m < 6; ++m) {
#pragma unroll
    for (int kc = 0; kc < 3; ++kc) {
      const short8 afr = *reinterpret_cast<const short8*>(
          Mb + (m * 16 + l15) * C_ + kc * 32 + quad * 8);
      acc[m] = __builtin_amdgcn_mfma_f32_16x16x32_bf16(afr, bfr[kc], acc[m], 0, 0, 0);
    }
  }
  float* ob = out + (size_t)b * C_ * N_ + gpix;
#pragma unroll
  for (int m = 0; m < 6; ++m) {
    const int chb = m * 16 + quad * 4;
#pragma unroll
    for (int r = 0; r < 4; ++r)
      ob[(size_t)(chb + r) * N_] = acc[m][r] + bias[chb + r];
  }
}

extern "C" void kernel_launch(void* const* d_in, const int* in_sizes, int n_in,
                              void* d_out, int out_size, void* d_ws, size_t ws_size,
                              hipStream_t stream) {
  const float* x      = (const float*)d_in[0];
  const float* qkv_w  = (const float*)d_in[1];
  const float* qkv_b  = (const float*)d_in[2];
  const float* dw_w   = (const float*)d_in[3];
  const float* dw_b   = (const float*)d_in[4];
  const float* proj_w = (const float*)d_in[5];
  const float* proj_b = (const float*)d_in[6];

  float* out      = (float*)d_out;                       // [4,96,256,256]
  float* attn_out = out + (size_t)B_ * C_ * N_;          // [4,3,32,32]

  // Workspace: A 151MB | inv 3KB | part 6.3MB | wq_bf 55KB | Mbf 74KB
  unsigned short* A = (unsigned short*)d_ws;
  float* inv   = (float*)(A + (size_t)B_ * C3_ * N_);
  float* part  = inv + 768;
  unsigned short* wq_bf = (unsigned short*)(part + SPLITS_ * B_ * HEAD_ * 1024);
  unsigned short* Mbf   = wq_bf + C3_ * C_;

  k_cast<<<108, 256, 0, stream>>>(qkv_w, wq_bf, C3_ * C_);
  k1_mfma<<<dim3(N_ / 128, B_), 512, 0, stream>>>(x, wq_bf, qkv_b, A);
  k_dw_reg<<<B_ * C3_, 256, 0, stream>>>(A, dw_w, dw_b, inv);
  k_attn_mfma<<<dim3(SPLITS_, HEAD_, B_), 256, 0, stream>>>(A, part);
  k_softmax<<<48, 256, 0, stream>>>(part, inv, attn_out);
  k_M<<<B_, 256, 0, stream>>>(attn_out, proj_w, Mbf);
  k7_mfma<<<dim3(N_ / 64, B_), 256, 0, stream>>>(A, Mbf, proj_b, out);
}